// Round 12
// baseline (103.829 us; speedup 1.0000x reference)
//
#include <hip/hip_runtime.h>

#define LOG2E 1.4426950408889634f
#define NEGBIG -3.0e38f

typedef float  f32x4  __attribute__((ext_vector_type(4)));
typedef float  f32x16 __attribute__((ext_vector_type(16)));
typedef short  bf16x8 __attribute__((ext_vector_type(8)));
typedef unsigned short u16x4 __attribute__((ext_vector_type(4)));
typedef int    i32x4  __attribute__((ext_vector_type(4)));
typedef unsigned int u32x2 __attribute__((ext_vector_type(2)));

__device__ __forceinline__ unsigned short f2bf(float f) {
  union { float f; unsigned u; } v; v.f = f;
  unsigned r = v.u + 0x7FFFu + ((v.u >> 16) & 1u);
  return (unsigned short)(r >> 16);
}

__device__ __forceinline__ unsigned cvtpk(float a, float b) {
  unsigned r;
  asm("v_cvt_pk_bf16_f32 %0, %1, %2" : "=v"(r) : "v"(a), "v"(b));
  return r;
}

__device__ __forceinline__ bf16x8 load_cvt8(const float* p) {
  f32x4 a = *(const f32x4*)p;
  f32x4 b = *(const f32x4*)(p + 4);
  bf16x8 r;
  r[0]=(short)f2bf(a[0]); r[1]=(short)f2bf(a[1]); r[2]=(short)f2bf(a[2]); r[3]=(short)f2bf(a[3]);
  r[4]=(short)f2bf(b[0]); r[5]=(short)f2bf(b[1]); r[6]=(short)f2bf(b[2]); r[7]=(short)f2bf(b[3]);
  return r;
}

// ---------------------------------------------------------------------------
// Kernel 1: QKV projection (R8 version, known-good).
// mode 0: Q -> Q[B][H][N][32] linear. mode 1: K -> fragment order.
// mode 2: V -> fragment order. (Fragment order = attn loads are lane*16B.)
// ---------------------------------------------------------------------------
__global__ __launch_bounds__(256) void qkv_kernel(
    const float* __restrict__ x,
    const float* __restrict__ wq, const float* __restrict__ wk, const float* __restrict__ wv,
    unsigned short* __restrict__ Qo, unsigned short* __restrict__ Ko,
    unsigned short* __restrict__ Vto)
{
  const int mode = blockIdx.y;
  const int n0   = blockIdx.x * 64;
  const int b    = n0 >> 11;
  const int nl0  = n0 & 2047;
  const int wave = threadIdx.x >> 6;
  const int lane = threadIdx.x & 63;
  const int li = lane & 15, qt = lane >> 4;

  f32x4 acc[4][4];
#pragma unroll
  for (int i = 0; i < 4; i++)
#pragma unroll
    for (int j = 0; j < 4; j++) acc[i][j] = (f32x4)0.0f;

  if (mode < 2) {
    const float* w = mode ? wk : wq;
    const float osc = mode ? 1.0f : (1.4426950408889634f / 5.656854249492381f);
#pragma unroll
    for (int ks = 0; ks < 8; ks++) {
      bf16x8 af[4], bfr[4];
#pragma unroll
      for (int dm = 0; dm < 4; dm++)
        af[dm] = load_cvt8(w + (size_t)(wave*64 + dm*16 + li)*256 + ks*32 + qt*8);
#pragma unroll
      for (int nf = 0; nf < 4; nf++)
        bfr[nf] = load_cvt8(x + (size_t)(n0 + nf*16 + li)*256 + ks*32 + qt*8);
#pragma unroll
      for (int dm = 0; dm < 4; dm++)
#pragma unroll
        for (int nf = 0; nf < 4; nf++)
          acc[dm][nf] = __builtin_amdgcn_mfma_f32_16x16x32_bf16(af[dm], bfr[nf], acc[dm][nf], 0, 0, 0);
    }
#pragma unroll
    for (int dm = 0; dm < 4; dm++) {
      const int dbase = wave*64 + dm*16 + qt*4;
      const int h = dbase >> 5, dk = dbase & 31;
#pragma unroll
      for (int nf = 0; nf < 4; nf++) {
        const int nl = nl0 + nf*16 + li;
        u16x4 o;
#pragma unroll
        for (int r = 0; r < 4; r++) o[r] = f2bf(acc[dm][nf][r] * osc);
        if (mode == 0) {
          *(u16x4*)(Qo + ((size_t)(b*8 + h)*2048 + nl)*32 + dk) = o;
        } else {
          const size_t addr = (size_t)(b*8 + h)*65536
              + (size_t)(nl >> 5)*1024 + (size_t)((dk >> 4) & 1)*512
              + (size_t)((nl & 31) + 32*((dk >> 3) & 1))*8 + (dk & 7);
          *(u16x4*)(Ko + addr) = o;
        }
      }
    }
  } else {
#pragma unroll
    for (int ks = 0; ks < 8; ks++) {
      bf16x8 af[4], bfr[4];
#pragma unroll
      for (int nm = 0; nm < 4; nm++)
        af[nm] = load_cvt8(x + (size_t)(n0 + nm*16 + li)*256 + ks*32 + qt*8);
#pragma unroll
      for (int df = 0; df < 4; df++)
        bfr[df] = load_cvt8(wv + (size_t)(wave*64 + df*16 + li)*256 + ks*32 + qt*8);
#pragma unroll
      for (int nm = 0; nm < 4; nm++)
#pragma unroll
        for (int df = 0; df < 4; df++)
          acc[nm][df] = __builtin_amdgcn_mfma_f32_16x16x32_bf16(af[nm], bfr[df], acc[nm][df], 0, 0, 0);
    }
#pragma unroll
    for (int nm = 0; nm < 4; nm++) {
      const int nl = nl0 + nm*16 + qt*4;
#pragma unroll
      for (int df = 0; df < 4; df++) {
        const int d = wave*64 + df*16 + li;
        const int h = d >> 5, dv = d & 31;
        u16x4 o;
#pragma unroll
        for (int r = 0; r < 4; r++) o[r] = f2bf(acc[nm][df][r]);
        const size_t addr = (size_t)(b*8 + h)*65536
            + (size_t)(nl >> 5)*1024 + (size_t)((nl >> 4) & 1)*512
            + (size_t)(((nl >> 3) & 1)*32 + dv)*8 + (nl & 7);
        *(u16x4*)(Vto + addr) = o;
      }
    }
  }
}

// ---------------------------------------------------------------------------
// Kernel 2: fused flash attention. q-tile 32 REAL, 32x32x16 MFMA, streaming
// softmax, cvt_pk+permlane PV, fragment-coalesced Kf/Vf — all R11-verified.
// NEW vs R11: 4 heads per block (4 waves, 256 thr), grid 512 = 2 INDEPENDENT
// blocks/CU (separate barrier domains fill each other's stalls). me tile
// (32q x 128k, C2-XOR layout, double-buffered) staged per block; staging map
// re-derived for 256 threads (4 chunks/thread: +64 floats for q+16, +2048
// for k+64 — exact offsets in the element-checked layout).
// Sync = __syncthreads() only.
// ---------------------------------------------------------------------------
__global__ __launch_bounds__(256, 2) void attn_kernel(
    const unsigned short* __restrict__ Qg,   // [B][H][N][32] linear
    const unsigned short* __restrict__ Kf,   // fragment order, 65536/head
    const unsigned short* __restrict__ Vf,   // fragment order, 65536/head
    const float* __restrict__ edge,          // [B][N][N]
    const int*   __restrict__ mask,          // [B][N][N]
    unsigned short* __restrict__ Og)         // [B][N][256]
{
  __shared__ __attribute__((aligned(16))) float me_s[2][4096];  // 2 x (32q x 128k)

  const int bid = blockIdx.x;        // 512 blocks: qi*8 + b*2 + hg
  const int b  = (bid >> 1) & 3;     // XCD-pinned batch
  const int hg = bid & 1;            // head group (0: h0..3, 1: h4..7)
  const int qi = bid >> 3;           // 0..63
  const int q0 = qi * 32;
  const int tid  = threadIdx.x;
  const int wave = tid >> 6;         // 0..3
  const int lane = tid & 63;
  const int ql = lane & 31, hi = lane >> 5;
  const int h = hg*4 + wave;

  const unsigned short* qbase = Qg + ((size_t)(b*8 + h)*2048 + q0)*32;
  const unsigned short* kf = Kf + (size_t)(b*8 + h)*65536 + lane*8;
  const unsigned short* vf = Vf + (size_t)(b*8 + h)*65536 + lane*8;

  // staging map: thread t (0..255) -> q = t>>4 (0..15), k4 = (t&15)*4.
  // 4 chunks: (q,k4), (q+16,k4), (q,k4+64), (q+16,k4+64).
  const int q_s = tid >> 4;
  const int k4  = (tid & 15) * 4;
  const float* eaddr = edge + ((size_t)b*2048 + q0 + q_s)*2048 + k4;
  const int*   maddr = mask + ((size_t)b*2048 + q0 + q_s)*2048 + k4;
  const float* eaddr2 = eaddr + 16*2048;       // q+16 row
  const int*   maddr2 = maddr + 16*2048;
  // me layout per 32-key tile T (1024 floats): quad (q, k4) ->
  //   C2 = ((k&31)>>3)*2 + ((k>>2)&1); idx = T*1024 + (C2*32 + (q^C2))*4 + (k&3)
  const int sC2  = (((k4 & 31) >> 3) * 2) + ((k4 >> 2) & 1);
  const int widx = (k4 >> 5)*1024 + (sC2*32 + (q_s ^ sC2))*4;
  // chunk offsets: q+16 -> +64 floats (sC2<8, no carry); k+64 -> +2048 floats.
  // C-in read float-offsets per rg (C2 = rg*2+hi); add T*1024 at use site
  int rix[4];
#pragma unroll
  for (int rg = 0; rg < 4; rg++) {
    const int C2 = rg*2 + hi;
    rix[rg] = (C2*32 + (ql ^ C2)) * 4;
  }

  // Q B-fragments
  const bf16x8 qf0 = *(const bf16x8*)(qbase + (size_t)ql*32 +  0 + hi*8);
  const bf16x8 qf1 = *(const bf16x8*)(qbase + (size_t)ql*32 + 16 + hi*8);

#define STAGE_CONV_WRITE(BUF, E00, M00, E10, M10, E01, M01, E11, M11)         \
  {                                                                           \
    f32x4 w00, w10, w01, w11;                                                 \
    _Pragma("unroll")                                                         \
    for (int r = 0; r < 4; r++) {                                             \
      w00[r] = M00[r] ? E00[r]*LOG2E : NEGBIG;                                \
      w10[r] = M10[r] ? E10[r]*LOG2E : NEGBIG;                                \
      w01[r] = M01[r] ? E01[r]*LOG2E : NEGBIG;                                \
      w11[r] = M11[r] ? E11[r]*LOG2E : NEGBIG;                                \
    }                                                                         \
    *(f32x4*)&me_s[BUF][widx]        = w00;                                   \
    *(f32x4*)&me_s[BUF][widx + 64]   = w10;                                   \
    *(f32x4*)&me_s[BUF][widx + 2048] = w01;                                   \
    *(f32x4*)&me_s[BUF][widx + 2112] = w11;                                   \
  }

  { // stage phase 0 (keys 0..127)
    f32x4 e00 = *(const f32x4*)eaddr;        i32x4 m00 = *(const i32x4*)maddr;
    f32x4 e10 = *(const f32x4*)eaddr2;       i32x4 m10 = *(const i32x4*)maddr2;
    f32x4 e01 = *(const f32x4*)(eaddr + 64); i32x4 m01 = *(const i32x4*)(maddr + 64);
    f32x4 e11 = *(const f32x4*)(eaddr2 + 64);i32x4 m11 = *(const i32x4*)(maddr2 + 64);
    STAGE_CONV_WRITE(0, e00, m00, e10, m10, e01, m01, e11, m11)
  }
  __syncthreads();

  // issue phase-1 edge/mask loads
  f32x4 se00 = *(const f32x4*)(eaddr + 128);  i32x4 sm00 = *(const i32x4*)(maddr + 128);
  f32x4 se10 = *(const f32x4*)(eaddr2 + 128); i32x4 sm10 = *(const i32x4*)(maddr2 + 128);
  f32x4 se01 = *(const f32x4*)(eaddr + 192);  i32x4 sm01 = *(const i32x4*)(maddr + 192);
  f32x4 se11 = *(const f32x4*)(eaddr2 + 192); i32x4 sm11 = *(const i32x4*)(maddr2 + 192);

  // preload K tile 0
  bf16x8 kXa = *(const bf16x8*)(kf);
  bf16x8 kXb = *(const bf16x8*)(kf + 512);
  bf16x8 kYa, kYb;

  float lsum = 0.f;
  f32x16 oacc = (f32x16)0.0f;

  union CU { f32x16 v; f32x4 q[4]; };

#define PV_KS(SV, HALF, VA)                                                   \
  {                                                                           \
    unsigned a0 = cvtpk(SV[(HALF)*8+0], SV[(HALF)*8+1]);                      \
    unsigned a1 = cvtpk(SV[(HALF)*8+2], SV[(HALF)*8+3]);                      \
    unsigned b0 = cvtpk(SV[(HALF)*8+4], SV[(HALF)*8+5]);                      \
    unsigned b1 = cvtpk(SV[(HALF)*8+6], SV[(HALF)*8+7]);                      \
    u32x2 p0 = __builtin_amdgcn_permlane32_swap(a0, b0, false, false);        \
    u32x2 p1 = __builtin_amdgcn_permlane32_swap(a1, b1, false, false);        \
    i32x4 pw4;                                                                \
    pw4[0] = (int)p0[0]; pw4[1] = (int)p1[0];                                 \
    pw4[2] = (int)p0[1]; pw4[3] = (int)p1[1];                                 \
    const bf16x8 pf = __builtin_bit_cast(bf16x8, pw4);                        \
    oacc = __builtin_amdgcn_mfma_f32_32x32x16_bf16(VA, pf, oacc, 0, 0, 0);    \
  }

#define GROUP(KB, T, KCa, KCb, KNa, KNb)                                      \
  {                                                                           \
    const size_t nxt = (size_t)(((KB) + 1) & 63) * 1024;                      \
    KNa = *(const bf16x8*)(kf + nxt);                                         \
    KNb = *(const bf16x8*)(kf + nxt + 512);                                   \
    const bf16x8 vA0 = *(const bf16x8*)(vf + (size_t)(KB)*1024);              \
    const bf16x8 vA1 = *(const bf16x8*)(vf + (size_t)(KB)*1024 + 512);        \
    CU c;                                                                     \
    _Pragma("unroll")                                                         \
    for (int rg = 0; rg < 4; rg++)                                            \
      c.q[rg] = *(const f32x4*)(mb + (T)*1024 + rix[rg]);                     \
    f32x16 s = __builtin_amdgcn_mfma_f32_32x32x16_bf16(KCa, qf0, c.v, 0, 0, 0); \
    s = __builtin_amdgcn_mfma_f32_32x32x16_bf16(KCb, qf1, s, 0, 0, 0);        \
    _Pragma("unroll")                                                         \
    for (int i = 0; i < 16; i++) s[i] = __builtin_amdgcn_exp2f(s[i]);         \
    {                                                                         \
      float r0 = 0.f, r1 = 0.f, r2 = 0.f, r3 = 0.f;                           \
      _Pragma("unroll")                                                       \
      for (int i = 0; i < 4; i++) {                                           \
        r0 += s[4*i]; r1 += s[4*i+1]; r2 += s[4*i+2]; r3 += s[4*i+3];         \
      }                                                                       \
      lsum += (r0 + r1) + (r2 + r3);                                          \
    }                                                                         \
    PV_KS(s, 0, vA0)                                                          \
    PV_KS(s, 1, vA1)                                                          \
  }

  for (int p = 0; p < 16; ++p) {
    const float* mb = &me_s[p & 1][0];
    // write NEXT phase's buffer (data loaded 1 phase ago)
    if (p < 15) {
      STAGE_CONV_WRITE((p + 1) & 1, se00, sm00, se10, sm10, se01, sm01, se11, sm11)
    }
    if (p < 14) { // issue loads for phase p+2
      const int ofs = (p + 2)*128;
      se00 = *(const f32x4*)(eaddr + ofs);       sm00 = *(const i32x4*)(maddr + ofs);
      se10 = *(const f32x4*)(eaddr2 + ofs);      sm10 = *(const i32x4*)(maddr2 + ofs);
      se01 = *(const f32x4*)(eaddr + ofs + 64);  sm01 = *(const i32x4*)(maddr + ofs + 64);
      se11 = *(const f32x4*)(eaddr2 + ofs + 64); sm11 = *(const i32x4*)(maddr2 + ofs + 64);
    }
    const int g0 = p * 4;
    GROUP(g0,     0, kXa, kXb, kYa, kYb)
    GROUP(g0 + 1, 1, kYa, kYb, kXa, kXb)
    GROUP(g0 + 2, 2, kXa, kXb, kYa, kYb)
    GROUP(g0 + 3, 3, kYa, kYb, kXa, kXb)
    __syncthreads();
  }
#undef GROUP
#undef PV_KS
#undef STAGE_CONV_WRITE

  const float ltot = lsum + __shfl_xor(lsum, 32);
  const float rl = 1.0f / ltot;
  // O^T: lane holds col q = q0+ql, rows d = (r&3) + 8*rg + 4*hi
#pragma unroll
  for (int rg = 0; rg < 4; rg++) {
    u16x4 o;
#pragma unroll
    for (int r = 0; r < 4; r++) o[r] = f2bf(oacc[rg*4 + r] * rl);
    *(u16x4*)(Og + ((size_t)(b*2048 + q0 + ql))*256 + h*32 + rg*8 + hi*4) = o;
  }
}

// ---------------------------------------------------------------------------
// Kernel 3: output projection (unchanged, known-good).
// ---------------------------------------------------------------------------
__global__ __launch_bounds__(256) void proj_kernel(
    const unsigned short* __restrict__ O,    // [8192][256] bf16
    const float* __restrict__ wo, const float* __restrict__ bo,
    float* __restrict__ Y)                   // [8192][256] f32
{
  const int n0   = blockIdx.x * 64;
  const int wave = threadIdx.x >> 6;
  const int lane = threadIdx.x & 63;
  const int li = lane & 15, qt = lane >> 4;

  f32x4 acc[4][4];
#pragma unroll
  for (int i = 0; i < 4; i++)
#pragma unroll
    for (int j = 0; j < 4; j++) acc[i][j] = (f32x4)0.0f;

#pragma unroll
  for (int ks = 0; ks < 8; ks++) {
    bf16x8 af[4], bfr[4];
#pragma unroll
    for (int dm = 0; dm < 4; dm++)
      af[dm] = load_cvt8(wo + (size_t)(wave*64 + dm*16 + li)*256 + ks*32 + qt*8);
#pragma unroll
    for (int nf = 0; nf < 4; nf++)
      bfr[nf] = *(const bf16x8*)(O + (size_t)(n0 + nf*16 + li)*256 + ks*32 + qt*8);
#pragma unroll
    for (int dm = 0; dm < 4; dm++)
#pragma unroll
      for (int nf = 0; nf < 4; nf++)
        acc[dm][nf] = __builtin_amdgcn_mfma_f32_16x16x32_bf16(af[dm], bfr[nf], acc[dm][nf], 0, 0, 0);
  }

#pragma unroll
  for (int dm = 0; dm < 4; dm++) {
    const int d0 = wave*64 + dm*16 + qt*4;
    const f32x4 bo4 = *(const f32x4*)(bo + d0);
#pragma unroll
    for (int nf = 0; nf < 4; nf++) {
      const int n = n0 + nf*16 + li;
      f32x4 y = acc[dm][nf] + bo4;
      *(f32x4*)(Y + (size_t)n*256 + d0) = y;
    }
  }
}

// ---------------------------------------------------------------------------
extern "C" void kernel_launch(void* const* d_in, const int* in_sizes, int n_in,
                              void* d_out, int out_size, void* d_ws, size_t ws_size,
                              hipStream_t stream) {
  const float* x  = (const float*)d_in[0];
  const float* ew = (const float*)d_in[1];
  const int*   mk = (const int*)d_in[2];
  const float* wq = (const float*)d_in[3];
  const float* wk = (const float*)d_in[4];
  const float* wv = (const float*)d_in[5];
  const float* wo = (const float*)d_in[6];
  const float* bo = (const float*)d_in[7];
  float* y = (float*)d_out;

  unsigned short* Q  = (unsigned short*)d_ws;       // [4][8][2048][32] bf16
  unsigned short* Kf = Q  + 2097152;                // fragment order
  unsigned short* Vf = Kf + 2097152;                // fragment order
  unsigned short* O  = Vf + 2097152;                // [4][2048][256]  bf16

  qkv_kernel<<<dim3(128, 3), 256, 0, stream>>>(x, wq, wk, wv, Q, Kf, Vf);
  attn_kernel<<<512, 256, 0, stream>>>(Q, Kf, Vf, ew, mk, O);
  proj_kernel<<<128, 256, 0, stream>>>(O, wo, bo, y);
}